// Round 9
// baseline (100.965 us; speedup 1.0000x reference)
//
#include <hip/hip_runtime.h>
#include <math.h>

// ---------------- output offsets (floats) ----------------
#define O_Q     0
#define O_LOSS  2097152
#define O_IDX   2097153
#define O_PERP  2129921
#define O_NECS  2129922
#define O_EMAW  2130946
#define O_W     2196482

// ---------------- workspace offsets (4-byte units) ----------------
#define W_WT     0          // 65536  transposed weight [64][1024] fp32
#define W_SW2    65536      // 1024   (float, rounded from fp64)
#define W_IDX    66560      // 32768  (int)
#define W_CNT    99328      // 1024   counts
#define W_DW     100352     // 65536  dw
#define W_LOSS   165888     // 1      loss accum
#define W_ZN     66561      // floats to zero starting at W_CNT (cnt+dw+loss)

// =====================================================================
// kernel 0: transpose weight -> wT[64][1024]; wsq[c] = fl32(fp64 sum w^2);
// also zero counts/dw/loss region (replaces hipMemsetAsync dispatch).
// =====================================================================
__global__ __launch_bounds__(256)
void k_prep(const float* __restrict__ w, float* __restrict__ wT,
            float* __restrict__ wsq, float* __restrict__ zbase) {
    __shared__ float sh[64][65];
    int tid = threadIdx.x;
    int j0 = blockIdx.x * 64;
    for (int z = blockIdx.x * 256 + tid; z < W_ZN; z += 16 * 256) zbase[z] = 0.f;

    for (int p = 0; p < 16; ++p) {
        int f = p * 256 + tid;
        int j = f >> 6, d = f & 63;
        sh[j][d] = w[(j0 + j) * 64 + d];
    }
    __syncthreads();
    for (int p = 0; p < 16; ++p) {
        int f = p * 256 + tid;
        int d = f >> 6, jj = f & 63;
        wT[d * 1024 + j0 + jj] = sh[jj][d];
    }
    if (tid < 64) {
        double s = 0.0;
        #pragma unroll
        for (int d = 0; d < 64; ++d) {
            double v = (double)sh[tid][d];
            s = fma(v, v, s);
        }
        wsq[j0 + tid] = (float)s;
    }
}

// =====================================================================
// kernel 1: fp32 scores + argmin — barrier-free k-loop; waves split the
// CODE dimension (no duplicated w-reads across waves).
// grid 2048, block 256 = 4 waves; block covers 16 rows; wave ty owns
// code chunk ty*256, lane owns 4 codes, thread accumulates all 16 rows
// (acc[16][4]). Per wave per k-step: 1 coalesced 1KB w-load (L2-hot) +
// 4 broadcast x-reads -> VALU:VMEM ~4:1. LDS 4.6KB, ~6 waves/SIMD.
// Numerics bitwise-identical to round-4 PASSING kernel:
//   score = fl32( fl32(rsq[r]+wsq[c]) - 2*dot ), dot = seq fp32 FMA k=0..63,
//   rsq/wsq = fl32(fp64 sums), ties -> lowest code index.
// =====================================================================
__global__ __launch_bounds__(256, 4)
void k_dist(const float* __restrict__ x, const float* __restrict__ wT,
            const float* __restrict__ wsq,
            int* __restrict__ idx_int, float* __restrict__ out_idxf) {
    __shared__ float xs[64][16];     // [k][row] 4 KB
    __shared__ float rsq[16];
    __shared__ float bv[4][16];
    __shared__ int   bi[4][16];
    int tid = threadIdx.x;
    int tx = tid & 63, ty = tid >> 6;   // tx: 4 codes/lane; ty: 256-code chunk
    int cb = ty * 256;
    int rbase = blockIdx.x * 16;
    int b = rbase >> 10, hw0 = rbase & 1023;
    const float* xb = x + b * 65536 + hw0;

    // stage x tile: one float4 per thread (64 d x 16 r)
    {
        int d = tid >> 2, r4 = (tid & 3) << 2;
        *(float4*)&xs[d][r4] = *(const float4*)(xb + d * 1024 + r4);
    }
    __syncthreads();
    if (tid < 16) {                      // fp64 row norms, k ascending
        double s = 0.0;
        #pragma unroll
        for (int d = 0; d < 64; ++d) {
            double v = (double)xs[d][tid];
            s = fma(v, v, s);
        }
        rsq[tid] = (float)s;
    }
    __syncthreads();

    float acc[16][4];
    #pragma unroll
    for (int i = 0; i < 16; ++i)
        #pragma unroll
        for (int j = 0; j < 4; ++j) acc[i][j] = 0.f;

    const float4* wp = (const float4*)(wT + cb + tx * 4);   // + k*256 float4s
    #pragma unroll 4
    for (int k = 0; k < 64; ++k) {
        float4 wb  = wp[k * 256];            // coalesced 1KB/wave, L2-hot
        float4 xa0 = *(float4*)&xs[k][0];    // wave-uniform broadcasts
        float4 xa1 = *(float4*)&xs[k][4];
        float4 xa2 = *(float4*)&xs[k][8];
        float4 xa3 = *(float4*)&xs[k][12];
        float xr[16] = {xa0.x, xa0.y, xa0.z, xa0.w,
                        xa1.x, xa1.y, xa1.z, xa1.w,
                        xa2.x, xa2.y, xa2.z, xa2.w,
                        xa3.x, xa3.y, xa3.z, xa3.w};
        float wc[4]  = {wb.x, wb.y, wb.z, wb.w};
        #pragma unroll
        for (int i = 0; i < 16; ++i)
            #pragma unroll
            for (int j = 0; j < 4; ++j)
                acc[i][j] += xr[i] * wc[j];
    }

    // scoring; j ascending per thread => strict < keeps first min
    float4 wsa = *(const float4*)(wsq + cb + tx * 4);
    float s2v[4] = {wsa.x, wsa.y, wsa.z, wsa.w};
    float rq[16];
    #pragma unroll
    for (int i = 0; i < 16; ++i) rq[i] = rsq[i];

    float best[16];
    int   bidx[16];
    #pragma unroll
    for (int i = 0; i < 16; ++i) { best[i] = 3.4e38f; bidx[i] = 0; }
    #pragma unroll
    for (int j = 0; j < 4; ++j) {
        int c = cb + tx * 4 + j;
        float s2 = s2v[j];
        #pragma unroll
        for (int i = 0; i < 16; ++i) {
            float t1 = rq[i] + s2;              // fl32 add @ ~64
            float sc = t1 - 2.0f * acc[i][j];   // 2*dot exact; one rounding
            if (sc < best[i]) { best[i] = sc; bidx[i] = c; }
        }
    }

    // argmin reduce across 64 lanes (codes on lanes; tie -> lower index)
    #pragma unroll
    for (int off = 1; off < 64; off <<= 1) {
        #pragma unroll
        for (int i = 0; i < 16; ++i) {
            float ov = __shfl_xor(best[i], off);
            int   oi = __shfl_xor(bidx[i], off);
            if (ov < best[i] || (ov == best[i] && oi < bidx[i])) {
                best[i] = ov; bidx[i] = oi;
            }
        }
    }
    if (tx == 0) {
        #pragma unroll
        for (int i = 0; i < 16; ++i) { bv[ty][i] = best[i]; bi[ty][i] = bidx[i]; }
    }
    __syncthreads();
    // merge 4 waves; ty ascending = code-index ascending, so strict < keeps
    // the lowest index on ties (chunks are disjoint).
    if (tid < 16) {
        float bb = bv[0][tid]; int ii = bi[0][tid];
        #pragma unroll
        for (int t = 1; t < 4; ++t) {
            float ov = bv[t][tid]; int oi = bi[t][tid];
            if (ov < bb) { bb = ov; ii = oi; }
        }
        idx_int[rbase + tid]  = ii;
        out_idxf[rbase + tid] = (float)ii;
    }
}

// =====================================================================
// kernel 2: quantized output + loss + counts + dw (block = 64 vectors)
// xs stride 65 -> dw column reads are 2-way (free); round-4-verified.
// =====================================================================
__global__ __launch_bounds__(256)
void k_quant(const float* __restrict__ x, const float* __restrict__ w,
             const int* __restrict__ idx_int, float* __restrict__ outq,
             float* __restrict__ counts, float* __restrict__ dw,
             float* __restrict__ loss) {
    __shared__ float xs[64][65];
    __shared__ int   idxl[64];
    __shared__ float red[4];
    int tid = threadIdx.x;
    int n0  = blockIdx.x * 64;
    int b   = n0 >> 10, hw0 = n0 & 1023;
    const float* xb = x + b * 65536 + hw0;

    if (tid < 64) {
        int id = idx_int[n0 + tid];
        idxl[tid] = id;
        atomicAdd(&counts[id], 1.0f);
    }
    for (int p = 0; p < 16; ++p) {
        int f = p * 256 + tid;
        int d = f >> 6, n = f & 63;
        xs[d][n] = xb[d * 1024 + n];
    }
    __syncthreads();

    float ll = 0.f;
    for (int p = 0; p < 16; ++p) {
        int f = p * 256 + tid;
        int d = f >> 6, n = f & 63;
        float q  = w[idxl[n] * 64 + d];
        float xv = xs[d][n];
        float dd = q - xv;
        ll += dd * dd;
        outq[b * 65536 + d * 1024 + hw0 + n] = q;
    }
    #pragma unroll
    for (int off = 32; off; off >>= 1) ll += __shfl_down(ll, off);
    if ((tid & 63) == 0) red[tid >> 6] = ll;
    __syncthreads();
    if (tid == 0) atomicAdd(loss, red[0] + red[1] + red[2] + red[3]);

    // dw: lane = d, one coalesced 256B atomic row per vector
    int wv = tid >> 6, lane = tid & 63;
    for (int v = 0; v < 16; ++v) {
        int n = wv * 16 + v;
        atomicAdd(&dw[idxl[n] * 64 + lane], xs[lane][n]);
    }
}

// =====================================================================
// kernel 3 (merged): every block redundantly computes the cheap 1024-wide
// EMA/cluster-size reduction (2K L2 reads), then handles its own 256-elem
// slice of ema_w / new weight. Block 0 also writes NECS/PERP/LOSS.
// =====================================================================
__global__ __launch_bounds__(256)
void k_final(const float* __restrict__ ema_cs, const float* __restrict__ ema_w,
             const float* __restrict__ counts, const float* __restrict__ dw,
             const float* __restrict__ loss, float* __restrict__ out) {
    __shared__ float cs[1024];
    __shared__ float redA[4], redB[4];
    int tid = threadIdx.x;

    float necs[4];
    float s1 = 0.f, s2 = 0.f;
    #pragma unroll
    for (int q = 0; q < 4; ++q) {
        int j = q * 256 + tid;
        float c  = counts[j];
        float ne = 0.99f * ema_cs[j] + 0.01f * c;
        necs[q] = ne;
        float p = c * (1.0f / 32768.0f);
        s1 += ne;
        s2 += -p * logf(p + 1e-10f);
    }
    #pragma unroll
    for (int off = 32; off; off >>= 1) {
        s1 += __shfl_down(s1, off);
        s2 += __shfl_down(s2, off);
    }
    if ((tid & 63) == 0) { redA[tid >> 6] = s1; redB[tid >> 6] = s2; }
    __syncthreads();
    float ntot = redA[0] + redA[1] + redA[2] + redA[3];
    #pragma unroll
    for (int q = 0; q < 4; ++q)
        cs[q * 256 + tid] = (necs[q] + 1e-5f) / (ntot + 1024.0f * 1e-5f) * ntot;

    if (blockIdx.x == 0) {
        #pragma unroll
        for (int q = 0; q < 4; ++q) out[O_NECS + q * 256 + tid] = necs[q];
        if (tid == 0) {
            out[O_PERP] = expf(redB[0] + redB[1] + redB[2] + redB[3]);
            out[O_LOSS] = 0.25f * loss[0] * (1.0f / 2097152.0f);
        }
    }
    __syncthreads();

    int f = blockIdx.x * 256 + tid;
    int j = f >> 6;                      // wave-uniform -> broadcast cs read
    float ne = 0.99f * ema_w[f] + 0.01f * dw[f];
    out[O_EMAW + f] = ne;
    out[O_W + f]    = ne / cs[j];
}

// =====================================================================
extern "C" void kernel_launch(void* const* d_in, const int* in_sizes, int n_in,
                              void* d_out, int out_size, void* d_ws, size_t ws_size,
                              hipStream_t stream) {
    const float* x      = (const float*)d_in[0];
    const float* w      = (const float*)d_in[1];
    const float* ema_cs = (const float*)d_in[2];
    const float* ema_w  = (const float*)d_in[3];
    float* out = (float*)d_out;
    float* ws  = (float*)d_ws;

    float* wT     = ws + W_WT;
    float* wsq    = ws + W_SW2;
    int*   idxi   = (int*)(ws + W_IDX);
    float* counts = ws + W_CNT;
    float* dwb    = ws + W_DW;
    float* lossb  = ws + W_LOSS;

    k_prep <<<16,   256, 0, stream>>>(w, wT, wsq, counts);
    k_dist <<<2048, 256, 0, stream>>>(x, wT, wsq, idxi, out + O_IDX);
    k_quant<<<512,  256, 0, stream>>>(x, w, idxi, out + O_Q, counts, dwb, lossb);
    k_final<<<256,  256, 0, stream>>>(ema_cs, ema_w, counts, dwb, lossb, out);
}

// Round 10
// 74.740 us; speedup vs baseline: 1.3509x; 1.3509x over previous
//
#include <hip/hip_runtime.h>
#include <math.h>

typedef _Float16 half8 __attribute__((ext_vector_type(8)));
typedef _Float16 half4v __attribute__((ext_vector_type(4)));
typedef float    f32x4 __attribute__((ext_vector_type(4)));

// ---------------- output offsets (floats) ----------------
#define O_Q     0
#define O_LOSS  2097152
#define O_IDX   2097153
#define O_PERP  2129921
#define O_NECS  2129922
#define O_EMAW  2130946
#define O_W     2196482

// ---------------- workspace offsets (4-byte units) ----------------
#define W_WBF    0          // 65536 fl (=131072 halfs): B-fragments [64ct][4j][64l][8e]
#define W_SW2    65536      // 1024  wsq  (fl32 of fp64 sum)
#define W_RSQ    66560      // 32768 rsq  (fl32 of fp64 sum)
#define W_IDX    99328      // 32768 int
#define W_CNT    132096     // 1024  counts
#define W_DW     133120     // 65536 dw
#define W_LOSS   198656     // 1     loss
#define W_ZN     66561      // floats to zero starting at W_CNT

#define F16_MIN_NORM 6.103515625e-05f   // 2^-14

// =====================================================================
// kernel 0 (prep, grid 256):
//  blocks 0-63 : build B-fragment tensor (f16 hi/lo, MFMA layout)
//  blocks 0-15 : wsq[c] = fl32(fp64 sum w^2)
//  blocks 128+ : rsq[r] = fl32(fp64 sum x^2)   (k ascending)
//  all blocks  : zero counts/dw/loss
// =====================================================================
__global__ __launch_bounds__(256)
void k_prep(const float* __restrict__ w, const float* __restrict__ x,
            _Float16* __restrict__ wbf, float* __restrict__ wsq,
            float* __restrict__ rsq, float* __restrict__ zbase) {
    __shared__ float sh[64][65];
    int tid = threadIdx.x, blk = blockIdx.x;

    for (int z = blk * 256 + tid; z < W_ZN; z += 256 * 256) zbase[z] = 0.f;

    if (blk < 64) {
        int T  = blk * 256 + tid;           // 0..16383
        int ct = T >> 8, j = (T >> 6) & 3, l = T & 63;
        int kb = j & 1, isLo = j >> 1;
        int c  = ct * 16 + (l & 15), g = l >> 4;
        half8 o;
        #pragma unroll
        for (int e = 0; e < 8; ++e) {
            int kd = kb * 32 + g * 4 + (e & 3) + ((e >> 2) << 4);
            float wv = w[c * 64 + kd];
            _Float16 h = (fabsf(wv) >= F16_MIN_NORM) ? (_Float16)wv : (_Float16)0.f;
            if (isLo) {
                float hf = (float)h;
                o[e] = (_Float16)((wv - hf) * 16384.0f);   // lo scaled 2^14
            } else {
                o[e] = h;
            }
        }
        *(half8*)(wbf + ((ct * 4 + j) * 64 + l) * 8) = o;
    }

    if (blk < 16) {           // wsq
        int j0 = blk * 64;
        for (int p = 0; p < 16; ++p) {
            int f = p * 256 + tid;
            int j = f >> 6, d = f & 63;
            sh[j][d] = w[(j0 + j) * 64 + d];
        }
        __syncthreads();
        if (tid < 64) {
            double s = 0.0;
            #pragma unroll
            for (int d = 0; d < 64; ++d) {
                double v = (double)sh[tid][d];
                s = fma(v, v, s);
            }
            wsq[j0 + tid] = (float)s;
        }
    }

    if (blk >= 128) {         // rsq, one row per thread, d ascending
        int r = (blk - 128) * 256 + tid;
        const float* xp = x + (r >> 10) * 65536 + (r & 1023);
        double s = 0.0;
        #pragma unroll 8
        for (int d = 0; d < 64; ++d) {
            double v = (double)xp[d * 1024];
            s = fma(v, v, s);
        }
        rsq[r] = (float)s;
    }
}

// =====================================================================
// kernel 1: MFMA distances + argmin.
// grid 256 x 512 thr (8 waves); block = 128 rows; wave rt = 16 rows,
// iterates all 64 code-tiles. dot via 3-pass f16 split:
//   C1=xhi*whi, C2=xlo*whi (xlo scaled 2^11), C3=xhi*wlo (wlo scaled 2^14)
//   dot = C1 + C2*2^-11 + C3*2^-14    (err ~ r4's fp32-chain class)
// score = fl32( fl32(rsq[r]+wsq[c]) - 2*dot ); ties -> lowest code index.
// A/B frags built with the SAME (lane,e)->k map (k-permutation cancels);
// C/D layout: n=lane&15, m=(lane>>4)*4+reg  [m89/m91 verified].
// =====================================================================
__global__ __launch_bounds__(512, 2)
void k_dist(const float* __restrict__ x, const _Float16* __restrict__ wbf,
            const float* __restrict__ wsq, const float* __restrict__ rsq_g,
            int* __restrict__ idx_int, float* __restrict__ out_idxf) {
    __shared__ _Float16 xhi[64 * 128];
    __shared__ _Float16 xlo[64 * 128];
    int tid = threadIdx.x;
    int rbase = blockIdx.x * 128;
    int b = rbase >> 10, hw0 = rbase & 1023;
    const float* xb = x + b * 65536 + hw0;

    // stage x -> f16 hi/lo tiles (xlo scaled 2^11)
    #pragma unroll
    for (int p = 0; p < 4; ++p) {
        int f = p * 512 + tid;
        int d = f >> 5, r4 = (f & 31) << 2;
        float4 v = *(const float4*)(xb + d * 1024 + r4);
        float vv[4] = {v.x, v.y, v.z, v.w};
        half4v h, lo;
        #pragma unroll
        for (int q = 0; q < 4; ++q) {
            float xv = vv[q];
            _Float16 hh = (fabsf(xv) >= F16_MIN_NORM) ? (_Float16)xv : (_Float16)0.f;
            h[q]  = hh;
            lo[q] = (_Float16)((xv - (float)hh) * 2048.0f);
        }
        *(half4v*)&xhi[d * 128 + r4] = h;
        *(half4v*)&xlo[d * 128 + r4] = lo;
    }
    __syncthreads();

    int l = tid & 63, rt = tid >> 6;
    int g = l >> 4, n16 = l & 15;
    int m = rt * 16 + n16;

    // A fragments (once per wave-thread): [kb] x {hi, lo}
    half8 ahi[2], alo[2];
    #pragma unroll
    for (int kb = 0; kb < 2; ++kb) {
        #pragma unroll
        for (int e = 0; e < 8; ++e) {
            int kd = kb * 32 + g * 4 + (e & 3) + ((e >> 2) << 4);
            ahi[kb][e] = xhi[kd * 128 + m];
            alo[kb][e] = xlo[kd * 128 + m];
        }
    }

    float rq[4];
    #pragma unroll
    for (int i = 0; i < 4; ++i) rq[i] = rsq_g[rbase + rt * 16 + g * 4 + i];

    float best[4];
    int   bidx[4];
    #pragma unroll
    for (int i = 0; i < 4; ++i) { best[i] = 3.4e38f; bidx[i] = 0; }

    const half8* wv8 = (const half8*)wbf;
    #pragma unroll 1
    for (int ct = 0; ct < 64; ++ct) {
        const half8* wb = wv8 + ct * 256 + l;
        half8 bh0 = wb[0], bh1 = wb[64], bl0 = wb[128], bl1 = wb[192];

        f32x4 c1 = {0.f, 0.f, 0.f, 0.f};
        f32x4 c2 = {0.f, 0.f, 0.f, 0.f};
        f32x4 c3 = {0.f, 0.f, 0.f, 0.f};
        c1 = __builtin_amdgcn_mfma_f32_16x16x32_f16(ahi[0], bh0, c1, 0, 0, 0);
        c1 = __builtin_amdgcn_mfma_f32_16x16x32_f16(ahi[1], bh1, c1, 0, 0, 0);
        c2 = __builtin_amdgcn_mfma_f32_16x16x32_f16(alo[0], bh0, c2, 0, 0, 0);
        c2 = __builtin_amdgcn_mfma_f32_16x16x32_f16(alo[1], bh1, c2, 0, 0, 0);
        c3 = __builtin_amdgcn_mfma_f32_16x16x32_f16(ahi[0], bl0, c3, 0, 0, 0);
        c3 = __builtin_amdgcn_mfma_f32_16x16x32_f16(ahi[1], bl1, c3, 0, 0, 0);

        float wsqv = wsq[ct * 16 + n16];
        int n = ct * 16 + n16;
        #pragma unroll
        for (int i = 0; i < 4; ++i) {
            float dot = fmaf(c2[i], 4.8828125e-4f, c1[i]);      // +C2*2^-11
            dot = fmaf(c3[i], 6.103515625e-05f, dot);           // +C3*2^-14
            float t1 = rq[i] + wsqv;                            // fl32 add @ ~64
            float sc = fmaf(dot, -2.0f, t1);                    // one rounding
            if (sc < best[i]) { best[i] = sc; bidx[i] = n; }    // ct asc => first-min
        }
    }

    // reduce across the 16 lanes of each group (tie -> lower index)
    #pragma unroll
    for (int off = 1; off < 16; off <<= 1) {
        #pragma unroll
        for (int i = 0; i < 4; ++i) {
            float ov = __shfl_xor(best[i], off);
            int   oi = __shfl_xor(bidx[i], off);
            if (ov < best[i] || (ov == best[i] && oi < bidx[i])) {
                best[i] = ov; bidx[i] = oi;
            }
        }
    }
    if (n16 == 0) {
        #pragma unroll
        for (int i = 0; i < 4; ++i) {
            int r = rbase + rt * 16 + g * 4 + i;
            idx_int[r]  = bidx[i];
            out_idxf[r] = (float)bidx[i];
        }
    }
}

// =====================================================================
// kernel 2: quantized output + loss + counts + dw (block = 64 vectors)
// (round-4-verified, unchanged)
// =====================================================================
__global__ __launch_bounds__(256)
void k_quant(const float* __restrict__ x, const float* __restrict__ w,
             const int* __restrict__ idx_int, float* __restrict__ outq,
             float* __restrict__ counts, float* __restrict__ dw,
             float* __restrict__ loss) {
    __shared__ float xs[64][65];
    __shared__ int   idxl[64];
    __shared__ float red[4];
    int tid = threadIdx.x;
    int n0  = blockIdx.x * 64;
    int b   = n0 >> 10, hw0 = n0 & 1023;
    const float* xb = x + b * 65536 + hw0;

    if (tid < 64) {
        int id = idx_int[n0 + tid];
        idxl[tid] = id;
        atomicAdd(&counts[id], 1.0f);
    }
    for (int p = 0; p < 16; ++p) {
        int f = p * 256 + tid;
        int d = f >> 6, n = f & 63;
        xs[d][n] = xb[d * 1024 + n];
    }
    __syncthreads();

    float ll = 0.f;
    for (int p = 0; p < 16; ++p) {
        int f = p * 256 + tid;
        int d = f >> 6, n = f & 63;
        float q  = w[idxl[n] * 64 + d];
        float xv = xs[d][n];
        float dd = q - xv;
        ll += dd * dd;
        outq[b * 65536 + d * 1024 + hw0 + n] = q;
    }
    #pragma unroll
    for (int off = 32; off; off >>= 1) ll += __shfl_down(ll, off);
    if ((tid & 63) == 0) red[tid >> 6] = ll;
    __syncthreads();
    if (tid == 0) atomicAdd(loss, red[0] + red[1] + red[2] + red[3]);

    int wv = tid >> 6, lane = tid & 63;
    for (int v = 0; v < 16; ++v) {
        int n = wv * 16 + v;
        atomicAdd(&dw[idxl[n] * 64 + lane], xs[lane][n]);
    }
}

// =====================================================================
// kernel 3 (merged finalize, round-9-verified, unchanged)
// =====================================================================
__global__ __launch_bounds__(256)
void k_final(const float* __restrict__ ema_cs, const float* __restrict__ ema_w,
             const float* __restrict__ counts, const float* __restrict__ dw,
             const float* __restrict__ loss, float* __restrict__ out) {
    __shared__ float cs[1024];
    __shared__ float redA[4], redB[4];
    int tid = threadIdx.x;

    float necs[4];
    float s1 = 0.f, s2 = 0.f;
    #pragma unroll
    for (int q = 0; q < 4; ++q) {
        int j = q * 256 + tid;
        float c  = counts[j];
        float ne = 0.99f * ema_cs[j] + 0.01f * c;
        necs[q] = ne;
        float p = c * (1.0f / 32768.0f);
        s1 += ne;
        s2 += -p * logf(p + 1e-10f);
    }
    #pragma unroll
    for (int off = 32; off; off >>= 1) {
        s1 += __shfl_down(s1, off);
        s2 += __shfl_down(s2, off);
    }
    if ((tid & 63) == 0) { redA[tid >> 6] = s1; redB[tid >> 6] = s2; }
    __syncthreads();
    float ntot = redA[0] + redA[1] + redA[2] + redA[3];
    #pragma unroll
    for (int q = 0; q < 4; ++q)
        cs[q * 256 + tid] = (necs[q] + 1e-5f) / (ntot + 1024.0f * 1e-5f) * ntot;

    if (blockIdx.x == 0) {
        #pragma unroll
        for (int q = 0; q < 4; ++q) out[O_NECS + q * 256 + tid] = necs[q];
        if (tid == 0) {
            out[O_PERP] = expf(redB[0] + redB[1] + redB[2] + redB[3]);
            out[O_LOSS] = 0.25f * loss[0] * (1.0f / 2097152.0f);
        }
    }
    __syncthreads();

    int f = blockIdx.x * 256 + tid;
    int j = f >> 6;
    float ne = 0.99f * ema_w[f] + 0.01f * dw[f];
    out[O_EMAW + f] = ne;
    out[O_W + f]    = ne / cs[j];
}

// =====================================================================
extern "C" void kernel_launch(void* const* d_in, const int* in_sizes, int n_in,
                              void* d_out, int out_size, void* d_ws, size_t ws_size,
                              hipStream_t stream) {
    const float* x      = (const float*)d_in[0];
    const float* w      = (const float*)d_in[1];
    const float* ema_cs = (const float*)d_in[2];
    const float* ema_w  = (const float*)d_in[3];
    float* out = (float*)d_out;
    float* ws  = (float*)d_ws;

    _Float16* wbf  = (_Float16*)(ws + W_WBF);
    float* wsq     = ws + W_SW2;
    float* rsqb    = ws + W_RSQ;
    int*   idxi    = (int*)(ws + W_IDX);
    float* counts  = ws + W_CNT;
    float* dwb     = ws + W_DW;
    float* lossb   = ws + W_LOSS;

    k_prep <<<256, 256, 0, stream>>>(w, x, wbf, wsq, rsqb, counts);
    k_dist <<<256, 512, 0, stream>>>(x, wbf, wsq, rsqb, idxi, out + O_IDX);
    k_quant<<<512, 256, 0, stream>>>(x, w, idxi, out + O_Q, counts, dwb, lossb);
    k_final<<<256, 256, 0, stream>>>(ema_cs, ema_w, counts, dwb, lossb, out);
}